// Round 1
// baseline (147.417 us; speedup 1.0000x reference)
//
#include <hip/hip_runtime.h>
#include <hip/hip_bf16.h>

#define B_   64
#define NW_  256
#define H_   768

#define AB_    (0.1f / 768.0f)   // ALPHA*BETA
#define OMB_   0.9f              // 1 - BETA
#define K1_    0.1f
#define BP_    1.2f
#define AVDL_  50.0f

typedef __bf16 bf16x4 __attribute__((ext_vector_type(4)));
typedef __bf16 bf16x8 __attribute__((ext_vector_type(8)));
typedef float  f32x4  __attribute__((ext_vector_type(4)));

// Workgroup barrier WITHOUT the vmcnt(0) drain __syncthreads() emits:
// LDS visibility across waves needs only lgkmcnt(0). VGPR-destined global
// prefetch loads stay in flight across the barrier; the compiler's
// fine-grained vmcnt(N) waits on register uses keep data deps correct.
#define BAR_LGKM() asm volatile("s_waitcnt lgkmcnt(0)\n\ts_barrier" ::: "memory")

// ---------------------------------------------------------------------------
// 128x64-tile GEMM, fused score epilogue (dot + exact-match), pipelined.
// R0 change: 256 blk x 256 thr (1 blk/CU, 1 wave/SIMD, 9% occupancy) was
// latency-bound — MfmaUtil 5%, VALUBusy 7%, HBM 19%, L2 13%: every ds_read /
// barrier-skew stall was exposed. Now 512 blocks x 512 threads:
// 2 INDEPENDENT blocks/CU x 8 waves = 16 waves/CU (4/SIMD): one block's
// barrier waits are hidden by the other block's waves.
// Grid: bid = t*64 + b -> XCD = b%8 (64%8==0): all 8 tiles of one batch on
// one XCD, 2 blocks/CU resident; batch slice lives in the 4 MB XCD-L2.
// Wave w computes the 32x32 quadrant (qm=w>>1 of 4, qn=w&1 of 2) over K=768.
// K-loop: 24 chunks of BK=32, FULLY unrolled (all slot/buf indices literal
// -> no scratch spill), depth-3 static register lookahead, lgkm-only
// barriers so prefetches never drain at chunk boundaries.
// ---------------------------------------------------------------------------
__global__ __launch_bounds__(512, 4) void gemm_fused(
    const float* __restrict__ q_rep, const float* __restrict__ d_rep,
    const int* __restrict__ q_ids, const int* __restrict__ d_ids,
    const int* __restrict__ d_tfs,
    float* __restrict__ S, float* __restrict__ ws_etdf)
{
    // Padded rows (40 bf16 = 80 B stride): 16B-aligned, <=2-way bank alias.
    __shared__ __align__(16) __bf16 As[2][128][40];   // 20 KB
    __shared__ __align__(16) __bf16 Bs[2][64][40];    // 10 KB
    __shared__ float mq_s[128];     // q null mask
    __shared__ float md_s[64];      // d null mask
    __shared__ float mdtf_s[64];    // md * tf
    __shared__ float tf_s[64];      // raw tf (em term is unmasked)
    __shared__ int4  qk_s[128];     // q id keys
    __shared__ int4  dk_s[64];      // d id keys

    const int tid  = threadIdx.x;
    const int wave = tid >> 6;
    const int lane = tid & 63;
    const int bid  = blockIdx.x;
    const int b    = bid & 63;
    const int t    = bid >> 6;          // tile 0..7
    const int m0   = (t & 1) * 128;     // 2 m-tiles of 128
    const int n0   = (t >> 1) * 64;     // 4 n-tiles of 64

    // Masks / keys / tf into LDS (visible after the first barrier).
    if (tid < 128) {
        int4 qa = *(const int4*)(q_ids + ((size_t)b * NW_ + m0 + tid) * 4);
        qk_s[tid] = qa;
        mq_s[tid] = (qa.x == 0 && qa.y == 0 && qa.z == 0 && qa.w == 0) ? 0.f : 1.f;
    } else if (tid < 192) {
        const int r = tid - 128;
        int4 da = *(const int4*)(d_ids + ((size_t)b * NW_ + n0 + r) * 4);
        dk_s[r] = da;
        float md = (da.x == 0 && da.y == 0 && da.z == 0 && da.w == 0) ? 0.f : 1.f;
        float tf = (float)d_tfs[(size_t)b * NW_ + n0 + r];
        md_s[r]   = md;
        tf_s[r]   = tf;
        mdtf_s[r] = md * tf;
    }

    // Staging map: A chunk = 128 rows x 32 floats, B chunk = 64 rows x 32.
    // Thread covers A rows {srow, 64+srow} and B row srow, 16 B segment sseg:
    // each wave instr covers 8 rows x 128 B — fully-used 128 B lines.
    const int srow = tid >> 3;          // 0..63
    const int sseg = tid & 7;           // 0..7
    const float* Abase = q_rep + ((size_t)b * NW_ + m0) * H_;
    const float* Bbase = d_rep + ((size_t)b * NW_ + n0) * H_;

    // Three STATIC lookahead slots — only ever indexed by literals.
    float4 ra0[2], ra1[2], ra2[2];
    float4 rb0, rb1, rb2;

    auto loadg = [&](float4 (&ra)[2], float4 &rb, int kc) {
#pragma unroll
        for (int i = 0; i < 2; ++i)
            ra[i] = *(const float4*)(Abase + (size_t)(i * 64 + srow) * H_
                                     + kc * 32 + sseg * 4);
        rb = *(const float4*)(Bbase + (size_t)srow * H_ + kc * 32 + sseg * 4);
    };
    auto stage = [&](float4 (&ra)[2], float4 &rb, int buf) {
#pragma unroll
        for (int i = 0; i < 2; ++i) {
            bf16x4 va = { (__bf16)ra[i].x, (__bf16)ra[i].y,
                          (__bf16)ra[i].z, (__bf16)ra[i].w };
            *(bf16x4*)&As[buf][i * 64 + srow][sseg * 4] = va;
        }
        bf16x4 vb = { (__bf16)rb.x, (__bf16)rb.y, (__bf16)rb.z, (__bf16)rb.w };
        *(bf16x4*)&Bs[buf][srow][sseg * 4] = vb;
    };

    f32x4 acc[2][2];
#pragma unroll
    for (int i = 0; i < 2; ++i)
#pragma unroll
        for (int j = 0; j < 2; ++j)
            acc[i][j] = (f32x4){0.f, 0.f, 0.f, 0.f};

    const int fr = lane & 15;
    const int fk = (lane >> 4) * 8;
    const int qm = wave >> 1;           // quadrant row 0..3 (32-row strips)
    const int qn = wave & 1;            // quadrant col 0..1 (32-col strips)

    // Pipeline prologue: 3 chunks in flight, chunk 0 staged.
    loadg(ra0, rb0, 0);
    loadg(ra1, rb1, 1);
    loadg(ra2, rb2, 2);
    stage(ra0, rb0, 0);
    BAR_LGKM();

    // Invariant: chunk x lives in slot x%3; slot kc%3 (chunk kc) was staged
    // at the end of iter kc-1 -> free to refill with chunk kc+3.
#pragma unroll
    for (int kc = 0; kc < 24; ++kc) {
        const int buf = kc & 1;
        if (kc < 21) {
            if (kc % 3 == 0)      loadg(ra0, rb0, kc + 3);
            else if (kc % 3 == 1) loadg(ra1, rb1, kc + 3);
            else                  loadg(ra2, rb2, kc + 3);
        }
        bf16x8 af[2], bfr[2];
#pragma unroll
        for (int t2 = 0; t2 < 2; ++t2) {
            af[t2]  = *(bf16x8*)&As[buf][qm * 32 + t2 * 16 + fr][fk];
            bfr[t2] = *(bf16x8*)&Bs[buf][qn * 32 + t2 * 16 + fr][fk];
        }
#pragma unroll
        for (int i = 0; i < 2; ++i)
#pragma unroll
            for (int j = 0; j < 2; ++j)
                acc[i][j] = __builtin_amdgcn_mfma_f32_16x16x32_bf16(
                    af[i], bfr[j], acc[i][j], 0, 0, 0);
        if (kc < 23) {
            const int nb = buf ^ 1;
            if ((kc + 1) % 3 == 0)      stage(ra0, rb0, nb);
            else if ((kc + 1) % 3 == 1) stage(ra1, rb1, nb);
            else                        stage(ra2, rb2, nb);
        }
        BAR_LGKM();
    }

    // Epilogue. C layout: col = lane&15, row = (lane>>4)*4 + reg.
    // etdf contribution per (row, col): AB*mq*md*v*tf + 0.9*em*tf.
    const int cn = lane & 15;
    const int qg = lane >> 4;
    float md_l[2], mdtf_l[2], tf_l[2];
    int4  dk_l[2];
#pragma unroll
    for (int j = 0; j < 2; ++j) {
        const int c = qn * 32 + j * 16 + cn;
        md_l[j]   = md_s[c];
        mdtf_l[j] = mdtf_s[c];
        tf_l[j]   = tf_s[c];
        dk_l[j]   = dk_s[c];
    }
    float* Sbase = S + ((size_t)b * NW_ + m0 + qm * 32) * NW_ + n0 + qn * 32;

    float rs[8];
#pragma unroll
    for (int i = 0; i < 2; ++i)
#pragma unroll
        for (int r = 0; r < 4; ++r) {
            const int row = i * 16 + qg * 4 + r;
            const float mq = mq_s[qm * 32 + row];
            const int4  qk = qk_s[qm * 32 + row];
            float sdot = 0.f, sem = 0.f;
#pragma unroll
            for (int j = 0; j < 2; ++j) {
                const float v = acc[i][j][r];
                Sbase[(size_t)row * NW_ + j * 16 + cn] = v * mq * md_l[j];
                sdot += v * mdtf_l[j];
                const int4 dk = dk_l[j];
                if (dk.x == qk.x && dk.y == qk.y && dk.z == qk.z && dk.w == qk.w)
                    sem += tf_l[j];
            }
            rs[i * 4 + r] = mq * AB_ * sdot + OMB_ * sem;
        }
    // Reduce over the 16 lanes of each quad-group (rows identical there).
#pragma unroll
    for (int off = 1; off <= 8; off <<= 1)
#pragma unroll
        for (int e = 0; e < 8; ++e)
            rs[e] += __shfl_xor(rs[e], off);
    if (cn == 0) {
#pragma unroll
        for (int i = 0; i < 2; ++i)
#pragma unroll
            for (int r = 0; r < 4; ++r)
                atomicAdd(&ws_etdf[(size_t)b * NW_ + m0 + qm * 32 + i * 16 + qg * 4 + r],
                          rs[i * 4 + r]);
    }
}

// ---------------------------------------------------------------------------
// Final: per batch, dl = sum(tf); dtw = 1.1*etdf/(etdf + K1*(1-Bp+Bp*dl/AVDL)
// + 1e-8); s[b] = sum_q qtw*dtw.  One wave per batch.
// ---------------------------------------------------------------------------
__global__ __launch_bounds__(64) void final_kernel(
    const float* __restrict__ ws_etdf, const int* __restrict__ d_tfs,
    const float* __restrict__ qtw, float* __restrict__ out)
{
    const int b = blockIdx.x;
    const int lane = threadIdx.x;

    float4 ev = *(const float4*)(ws_etdf + (size_t)b * NW_ + lane * 4);
    int4  tf4 = *(const int4*)(d_tfs   + (size_t)b * NW_ + lane * 4);
    float4 qv = *(const float4*)(qtw    + (size_t)b * NW_ + lane * 4);

    float dl = (float)(tf4.x + tf4.y + tf4.z + tf4.w);
#pragma unroll
    for (int off = 32; off; off >>= 1) dl += __shfl_xor(dl, off);

    const float c = K1_ * (1.f - BP_ + BP_ * dl / AVDL_);
    float ew[4] = {ev.x, ev.y, ev.z, ev.w};
    float qw[4] = {qv.x, qv.y, qv.z, qv.w};
    float s = 0.f;
#pragma unroll
    for (int j = 0; j < 4; ++j)
        s += qw[j] * (ew[j] * (1.f + K1_)) / (ew[j] + c + 1e-8f);
#pragma unroll
    for (int off = 32; off; off >>= 1) s += __shfl_xor(s, off);
    if (lane == 0) out[b] = s;
}

extern "C" void kernel_launch(void* const* d_in, const int* in_sizes, int n_in,
                              void* d_out, int out_size, void* d_ws, size_t ws_size,
                              hipStream_t stream)
{
    const float* q_rep = (const float*)d_in[0];
    const float* d_rep = (const float*)d_in[1];
    const float* qtw   = (const float*)d_in[2];
    const int*   q_ids = (const int*)d_in[3];
    const int*   d_ids = (const int*)d_in[4];
    const int*   d_tfs = (const int*)d_in[5];

    float* out = (float*)d_out;
    float* S   = out + B_;              // d_expanded_tf, [B, NW, NW]
    float* ws_etdf = (float*)d_ws;      // [B, NW] f32

    hipMemsetAsync(ws_etdf, 0, (size_t)B_ * NW_ * sizeof(float), stream);

    gemm_fused<<<512, 512, 0, stream>>>(q_rep, d_rep, q_ids, d_ids, d_tfs,
                                        S, ws_etdf);
    final_kernel<<<B_, 64, 0, stream>>>(ws_etdf, d_tfs, qtw, out);
}